// Round 10
// baseline (165.977 us; speedup 1.0000x reference)
//
#include <hip/hip_runtime.h>
#include <math.h>

#define HDIM 256
#define PDIM 256
#define BATCH 8
#define LSEQ 4096
#define MTOT (BATCH * LSEQ)   // 32768
#define NCHUNK 128
#define CHLEN 32              // NCHUNK*CHLEN == LSEQ

typedef __attribute__((ext_vector_type(8))) short bf16x8;   // 8 bf16 = 4 VGPRs
typedef __attribute__((ext_vector_type(4))) float f32x4;

__device__ __forceinline__ unsigned short f2bf(float f) {
    union { float f; unsigned int u; } v; v.f = f;
    unsigned int r = v.u + 0x7FFFu + ((v.u >> 16) & 1u);   // RNE
    return (unsigned short)(r >> 16);
}
__device__ __forceinline__ float bf2f(unsigned int lo16) {
    union { unsigned int u; float f; } v; v.u = lo16 << 16;
    return v.f;
}

// async global->LDS, 16B per lane; LDS dest is wave-uniform base + lane*16
__device__ __forceinline__ void gload_lds16(const void* g, void* l) {
    __builtin_amdgcn_global_load_lds(
        (const __attribute__((address_space(1))) void*)g,
        (__attribute__((address_space(3))) void*)l, 16, 0, 0);
}

// ---------------- merged setup: par + W1t + W2t in one launch ----------------
__global__ void wpack_k(const float* __restrict__ llr, const float* __restrict__ lim,
                        const float* __restrict__ ldl,
                        const float* __restrict__ Br, const float* __restrict__ Bi,
                        const float* __restrict__ Cr, const float* __restrict__ Ci,
                        unsigned short* __restrict__ W1t, unsigned short* __restrict__ W2t,
                        float* __restrict__ par) {
    int h = threadIdx.x;
    if (blockIdx.x < PDIM) {
        int p = blockIdx.x;
        float er = expf(llr[p]);
        float im = lim[p];
        float d  = expf(ldl[p]);
        float zr = -er * d, zi = im * d;
        float ea = expf(zr);
        float sz, cz; sincosf(zi, &sz, &cz);
        float ar = ea * cz, ai = ea * sz;
        float dr = -er, di = im;
        float den = dr * dr + di * di;
        float nr = ar - 1.0f, ni = ai;
        float cr = (nr * dr + ni * di) / den;
        float ci = (ni * dr - nr * di) / den;
        float br = Br[p * HDIM + h], bi = Bi[p * HDIM + h];
        W1t[(2 * p) * HDIM + h]     = f2bf(cr * br - ci * bi);
        W1t[(2 * p + 1) * HDIM + h] = f2bf(cr * bi + ci * br);
    } else if (blockIdx.x < 2 * PDIM) {
        int p = blockIdx.x - PDIM;
        W2t[h * (2 * PDIM) + 2 * p]     = f2bf(Cr[h * PDIM + p]);
        W2t[h * (2 * PDIM) + 2 * p + 1] = f2bf(-Ci[h * PDIM + p]);
    } else {
        int p = h;
        float er = expf(llr[p]);
        float im = lim[p];
        float d  = expf(ldl[p]);
        float zr = -er * d, zi = im * d;
        float ea = expf(zr);
        float sz, cz; sincosf(zi, &sz, &cz);
        float ar = ea * cz, ai = ea * sz;
        float dr = -er, di = im;
        float den = dr * dr + di * di;
        float nr = ar - 1.0f, ni = ai;
        float cr = (nr * dr + ni * di) / den;
        float ci = (ni * dr - nr * di) / den;
        float eC = expf((float)CHLEN * zr);
        float sC, cC;
        sincosf((float)CHLEN * zi, &sC, &cC);
        par[2 * p]            = ar;
        par[2 * p + 1]        = ai;
        par[512 + 2 * p]      = cr;
        par[512 + 2 * p + 1]  = ci;
        par[1024 + 2 * p]     = eC * cC;
        par[1024 + 2 * p + 1] = eC * sC;
    }
}

// ---------------- fused LayerNorm -> bf16 h ----------------
__global__ void ln_k(const float* __restrict__ u, unsigned short* __restrict__ hbf,
                     const float* __restrict__ gamma, const float* __restrict__ beta) {
    __shared__ float gS[HDIM], bS[HDIM];
    int t = threadIdx.x;
    gS[t] = gamma[t]; bS[t] = beta[t];
    int lane = t & 63, wv = t >> 6;
    int row = blockIdx.x * 4 + wv;
    float4 v = *(const float4*)(u + (size_t)row * HDIM + lane * 4);
    float s  = v.x + v.y + v.z + v.w;
    float sq = v.x * v.x + v.y * v.y + v.z * v.z + v.w * v.w;
    #pragma unroll
    for (int o = 1; o < 64; o <<= 1) { s += __shfl_xor(s, o); sq += __shfl_xor(sq, o); }
    float mu = s * (1.0f / HDIM);
    float rs = rsqrtf(sq * (1.0f / HDIM) - mu * mu + 1e-5f);
    __syncthreads();
    int c = lane * 4;
    ushort4 o;
    o.x = f2bf((v.x - mu) * rs * gS[c + 0] + bS[c + 0]);
    o.y = f2bf((v.y - mu) * rs * gS[c + 1] + bS[c + 1]);
    o.z = f2bf((v.z - mu) * rs * gS[c + 2] + bS[c + 2]);
    o.w = f2bf((v.w - mu) * rs * gS[c + 3] + bS[c + 3]);
    *(ushort4*)(hbf + (size_t)row * HDIM + c) = o;
}

// ---------------- fused GEMM1 + scan_reduce (R9, unchanged) ----------------
__launch_bounds__(256, 2)
__global__ void gemm1_reduce_k(const unsigned short* __restrict__ A,
                               const unsigned short* __restrict__ B,
                               unsigned short* __restrict__ Bu,
                               const float* __restrict__ par,
                               float* __restrict__ last) {
    __shared__ __align__(16) unsigned char smem[128 * 66 * 4];   // 33792 B
    unsigned short* As0 = (unsigned short*)smem;                  // As[2][128*32]
    unsigned short* Bs0 = (unsigned short*)(smem + 16384);        // Bs[2][128*32]
    unsigned int*   Cs  = (unsigned int*)smem;                    // overlay, post-loop
    const int t = threadIdx.x;

    constexpr int K = HDIM;        // 256
    constexpr int N = 512;

    // XCD-aware remap
    const int nbn  = (int)gridDim.x;
    const int flat = (int)blockIdx.y * nbn + (int)blockIdx.x;
    const int nwg  = nbn * (int)gridDim.y;
    const int tile = (flat & 7) * (nwg >> 3) + (flat >> 3);
    const int bn = tile % nbn, bm = tile / nbn;

    const int lane = t & 63, w = t >> 6;

    const int srow   = 32 * w + (lane >> 2);
    const int schunk = (lane & 3) ^ ((lane >> 3) & 3);
    const unsigned short* gA = A + (size_t)(bm * 128 + srow) * K + schunk * 8;
    const unsigned short* gB = B + (size_t)(bn * 128 + srow) * K + schunk * 8;
    const int l0 = (32 * w) * 32;
    const int l1 = (32 * w + 16) * 32;

    const int wm = (w & 1) * 64;
    const int wn = (w >> 1) * 64;
    const int mrow = lane & 15;
    const int rsw  = (mrow >> 1) & 3;
    const int cch  = lane >> 4;
    const int fcol = ((cch ^ rsw) * 8);

    f32x4 acc[4][4] = {};
    constexpr int NT = K / 32;     // 8

    gload_lds16(gA,          &As0[0 * 4096 + l0]);
    gload_lds16(gA + 16 * K, &As0[0 * 4096 + l1]);
    gload_lds16(gB,          &Bs0[0 * 4096 + l0]);
    gload_lds16(gB + 16 * K, &Bs0[0 * 4096 + l1]);

    #pragma unroll
    for (int tt = 0; tt < NT; ++tt) {
        const int cur = tt & 1;
        if (tt + 1 < NT) {
            const int k0 = (tt + 1) * 32;
            gload_lds16(gA + k0,          &As0[(cur ^ 1) * 4096 + l0]);
            gload_lds16(gA + 16 * K + k0, &As0[(cur ^ 1) * 4096 + l1]);
            gload_lds16(gB + k0,          &Bs0[(cur ^ 1) * 4096 + l0]);
            gload_lds16(gB + 16 * K + k0, &Bs0[(cur ^ 1) * 4096 + l1]);
            asm volatile("s_waitcnt vmcnt(4)" ::: "memory");
        } else {
            asm volatile("s_waitcnt vmcnt(0)" ::: "memory");
        }
        __builtin_amdgcn_sched_barrier(0);
        __builtin_amdgcn_s_barrier();
        __builtin_amdgcn_sched_barrier(0);

        bf16x8 fa[4], fb[4];
        #pragma unroll
        for (int i = 0; i < 4; i++) {
            fa[i] = *(const bf16x8*)&As0[cur * 4096 + (wm + i * 16 + mrow) * 32 + fcol];
            fb[i] = *(const bf16x8*)&Bs0[cur * 4096 + (wn + i * 16 + mrow) * 32 + fcol];
        }
        __builtin_amdgcn_s_setprio(1);
        #pragma unroll
        for (int i = 0; i < 4; i++)
            #pragma unroll
            for (int j = 0; j < 4; j++)
                acc[i][j] = __builtin_amdgcn_mfma_f32_16x16x32_bf16(fa[i], fb[j], acc[i][j], 0, 0, 0);
        __builtin_amdgcn_s_setprio(0);
        __builtin_amdgcn_sched_barrier(0);
        if (tt + 1 < NT) __builtin_amdgcn_s_barrier();
    }

    __syncthreads();   // all waves done with staging LDS -> safe to overlay Cs

    // epilogue 1: write Bu (unchanged) + same bf16 values into Cs
    unsigned short* CsUS = (unsigned short*)Cs;
    const int r0 = (lane >> 4) * 4;
    const int c0 = lane & 15;
    #pragma unroll
    for (int i = 0; i < 4; i++) {
        #pragma unroll
        for (int r = 0; r < 4; r++) {
            const int row_l = wm + i * 16 + r0 + r;
            const size_t rowoff = (size_t)(bm * 128 + row_l) * N;
            #pragma unroll
            for (int j = 0; j < 4; j++) {
                const int col_l = wn + j * 16 + c0;
                const unsigned short hv = f2bf(acc[i][j][r]);
                Bu[rowoff + bn * 128 + col_l] = hv;
                CsUS[row_l * 132 + col_l]     = hv;   // 132-ushort row stride (pad)
            }
        }
    }
    __syncthreads();

    // epilogue 2: wave g = chunk g; lane = local complex column
    const int g  = w;
    const int pg = bn * 64 + lane;                    // global complex p
    const float ar = par[2 * pg], ai = par[2 * pg + 1];
    float xr = 0.0f, xi = 0.0f;
    const unsigned int* crow = Cs + (size_t)(g * 32) * 66 + lane;
    #pragma unroll 8
    for (int j = 0; j < CHLEN; j++) {
        unsigned int v = crow[(size_t)j * 66];
        float vr = bf2f(v & 0xFFFFu), vi = bf2f(v >> 16);
        float nr = fmaf(ar, xr, fmaf(-ai, xi, vr));
        float ni = fmaf(ar, xi, fmaf(ai, xr, vi));
        xr = nr; xi = ni;
    }
    const int b  = (bm * 128) / LSEQ;                 // batch
    const int cg = ((bm * 128) % LSEQ) / CHLEN + g;   // global chunk
    *(float2*)(last + ((size_t)b * NCHUNK + cg) * 512 + 2 * pg) = make_float2(xr, xi);
}

// ---------------- scan pass 2 (unchanged) ----------------
__global__ void scan_carry_k(const float* __restrict__ last, float* __restrict__ prefix,
                             const float* __restrict__ par) {
    int p = threadIdx.x, b = blockIdx.x;
    float Ar = par[1024 + 2 * p], Ai = par[1024 + 2 * p + 1];
    float Pr = 0.0f, Pi = 0.0f;
    const float2* lp = (const float2*)(last + (size_t)b * NCHUNK * 512) + p;
    float2* pp = (float2*)(prefix + (size_t)b * NCHUNK * 512) + p;
    for (int c0 = 0; c0 < NCHUNK; c0 += 16) {
        float2 v[16];
        #pragma unroll
        for (int j = 0; j < 16; j++) v[j] = lp[(size_t)(c0 + j) * 256];
        #pragma unroll
        for (int j = 0; j < 16; j++) {
            pp[(size_t)(c0 + j) * 256] = make_float2(Pr, Pi);
            float nr = fmaf(Ar, Pr, fmaf(-Ai, Pi, v[j].x));
            float ni = fmaf(Ar, Pi, fmaf(Ai, Pr, v[j].y));
            Pr = nr; Pi = ni;
        }
    }
}

// ---------------- fused scan_apply + GEMM2 ----------------
// Phase A unchanged (R7/R9-verified). GEMM phase: DIRECT-GLOBAL fb from the
// L2-resident W2t (no Bs staging, no inline-asm, no setprio): the fully
// unrolled 16-step loop exposes 64 independent fb loads; at acc=32 VGPR and
// __launch_bounds__(256,4) (cap 128) the compiler prefetches ~3 tiles deep
// (R5-gemm1's depth-1 failure was acc=64 at the same cap - doesn't apply).
// LDS = Xs only (32 KB) -> 4 blocks/CU = 16 waves/CU, 2x the TLP of the
// Bs-staged version (R9: 57 us, Occ 20%). R5's est. ~47 us for this exact
// structure at HALF the occupancy bound is the supporting evidence.
__launch_bounds__(256, 4)
__global__ void apply_gemm2_k(const unsigned short* __restrict__ Bu,
                              const float* __restrict__ par,
                              const float* __restrict__ prefix,
                              const unsigned short* __restrict__ W2t,
                              const float* __restrict__ u, float* __restrict__ out) {
    __shared__ __align__(16) unsigned short Xs[32 * 512];     // 32 KB, swizzled
    const int t = threadIdx.x;
    const int lane = t & 63, w = t >> 6;
    const int c = blockIdx.x, b = blockIdx.y;
    const size_t row0 = (size_t)b * LSEQ + (size_t)c * CHLEN;

    // ---------- phase A: thread p = t owns complex column p ----------
    {
        const unsigned int* q = (const unsigned int*)(Bu + row0 * 512) + t;
        unsigned int vv[32];
        #pragma unroll
        for (int j = 0; j < 32; j++) vv[j] = q[(size_t)j * 256];
        const float2 P = ((const float2*)(prefix + ((size_t)b * NCHUNK + c) * 512))[t];
        const float ar = par[2 * t], ai = par[2 * t + 1];
        float xr = P.x, xi = P.y;
        #pragma unroll
        for (int j = 0; j < 32; j++) {
            float vr = bf2f(vv[j] & 0xFFFFu), vi = bf2f(vv[j] >> 16);
            float nr = fmaf(ar, xr, fmaf(-ai, xi, vr));
            float ni = fmaf(ar, xi, fmaf(ai, xr, vi));
            xr = nr; xi = ni;
            unsigned int pk = (unsigned int)f2bf(xr) | ((unsigned int)f2bf(xi) << 16);
            // Xs[j][.]: 16B-chunk = p>>2, swizzle ^= j&7, word = p&3
            *(unsigned int*)&Xs[j * 512 + ((((t >> 2) ^ (j & 7)) << 3) + (t & 3) * 2)] = pk;
        }
    }

    const int mrow = lane & 15, cch = lane >> 4;
    const unsigned short* gW = W2t + (size_t)(w * 64 + mrow) * 512 + cch * 8;

    f32x4 acc[2][4] = {};
    __syncthreads();            // Xs complete (the only barrier)

    #pragma unroll
    for (int tt = 0; tt < 16; tt++) {          // K=512; compiler-scheduled
        bf16x8 fa[2], fb[4];
        #pragma unroll
        for (int i = 0; i < 2; i++) {
            const int r = i * 16 + mrow;
            fa[i] = *(const bf16x8*)&Xs[r * 512 + (((tt * 4 + cch) ^ (r & 7)) << 3)];
        }
        #pragma unroll
        for (int j = 0; j < 4; j++)
            fb[j] = *(const bf16x8*)(gW + (size_t)j * 16 * 512 + tt * 32);
        #pragma unroll
        for (int i = 0; i < 2; i++)
            #pragma unroll
            for (int j = 0; j < 4; j++)
                acc[i][j] = __builtin_amdgcn_mfma_f32_16x16x32_bf16(fa[i], fb[j], acc[i][j], 0, 0, 0);
    }

    // epilogue: out = u + gelu(acc). Wave w owns out-cols 64w..64w+63.
    const int r0 = (lane >> 4) * 4, c0 = lane & 15;
    #pragma unroll
    for (int i = 0; i < 2; i++) {
        #pragma unroll
        for (int r = 0; r < 4; r++) {
            const size_t rowoff = (row0 + i * 16 + r0 + r) * HDIM;
            #pragma unroll
            for (int j = 0; j < 4; j++) {
                const int col = w * 64 + j * 16 + c0;
                float y = acc[i][j][r];
                float z = 0.7978845608f * fmaf(0.044715f * y * y, y, y);
                float e = __expf(2.0f * z);
                float th = 1.0f - 2.0f / (e + 1.0f);
                float g = 0.5f * y * (1.0f + th);
                out[rowoff + col] = u[rowoff + col] + g;
            }
        }
    }
}

extern "C" void kernel_launch(void* const* d_in, const int* in_sizes, int n_in,
                              void* d_out, int out_size, void* d_ws, size_t ws_size,
                              hipStream_t stream) {
    const float* u   = (const float*)d_in[0];
    const float* llr = (const float*)d_in[1];
    const float* lim = (const float*)d_in[2];
    const float* Br  = (const float*)d_in[3];
    const float* Bi  = (const float*)d_in[4];
    const float* Cr  = (const float*)d_in[5];
    const float* Ci  = (const float*)d_in[6];
    const float* ldl = (const float*)d_in[7];
    const float* gam = (const float*)d_in[8];
    const float* bet = (const float*)d_in[9];
    float* out = (float*)d_out;

    float* ws     = (float*)d_ws;
    float* par    = ws;                                     // 2048 floats
    float* last   = ws + 2048;                              // 2 MB
    float* prefix = last + (size_t)BATCH * NCHUNK * 512;    // 2 MB
    unsigned short* W1t = (unsigned short*)(prefix + (size_t)BATCH * NCHUNK * 512);
    unsigned short* W2t = W1t + 512 * HDIM;                 // [256][512]
    unsigned short* hbf = W2t + HDIM * 512;                 // [32768][256] bf16
    unsigned short* Bu  = hbf + (size_t)MTOT * HDIM;        // [32768][512] bf16

    ln_k<<<MTOT / 4, 256, 0, stream>>>(u, hbf, gam, bet);
    wpack_k<<<2 * PDIM + 1, HDIM, 0, stream>>>(llr, lim, ldl, Br, Bi, Cr, Ci, W1t, W2t, par);

    // fused GEMM1 + chunk-local scan reduction (writes Bu and last)
    gemm1_reduce_k<<<dim3(512 / 128, MTOT / 128), 256, 0, stream>>>(hbf, W1t, Bu, par, last);

    scan_carry_k<<<BATCH, PDIM, 0, stream>>>(last, prefix, par);

    // fused scan_apply + GEMM2: Xs-only LDS, direct-global fb, 4 blocks/CU
    apply_gemm2_k<<<dim3(NCHUNK, BATCH), 256, 0, stream>>>(Bu, par, prefix, W2t, u, out);
}

// Round 11
// 154.828 us; speedup vs baseline: 1.0720x; 1.0720x over previous
//
#include <hip/hip_runtime.h>
#include <math.h>

#define HDIM 256
#define PDIM 256
#define BATCH 8
#define LSEQ 4096
#define MTOT (BATCH * LSEQ)   // 32768
#define NCHUNK 128
#define CHLEN 32              // NCHUNK*CHLEN == LSEQ

typedef __attribute__((ext_vector_type(8))) short bf16x8;   // 8 bf16 = 4 VGPRs
typedef __attribute__((ext_vector_type(4))) float f32x4;

__device__ __forceinline__ unsigned short f2bf(float f) {
    union { float f; unsigned int u; } v; v.f = f;
    unsigned int r = v.u + 0x7FFFu + ((v.u >> 16) & 1u);   // RNE
    return (unsigned short)(r >> 16);
}
__device__ __forceinline__ float bf2f(unsigned int lo16) {
    union { unsigned int u; float f; } v; v.u = lo16 << 16;
    return v.f;
}

// async global->LDS, 16B per lane; LDS dest is wave-uniform base + lane*16
__device__ __forceinline__ void gload_lds16(const void* g, void* l) {
    __builtin_amdgcn_global_load_lds(
        (const __attribute__((address_space(1))) void*)g,
        (__attribute__((address_space(3))) void*)l, 16, 0, 0);
}

// ---------------- merged setup: par + W1t + W2t in one launch ----------------
__global__ void wpack_k(const float* __restrict__ llr, const float* __restrict__ lim,
                        const float* __restrict__ ldl,
                        const float* __restrict__ Br, const float* __restrict__ Bi,
                        const float* __restrict__ Cr, const float* __restrict__ Ci,
                        unsigned short* __restrict__ W1t, unsigned short* __restrict__ W2t,
                        float* __restrict__ par) {
    int h = threadIdx.x;
    if (blockIdx.x < PDIM) {
        int p = blockIdx.x;
        float er = expf(llr[p]);
        float im = lim[p];
        float d  = expf(ldl[p]);
        float zr = -er * d, zi = im * d;
        float ea = expf(zr);
        float sz, cz; sincosf(zi, &sz, &cz);
        float ar = ea * cz, ai = ea * sz;
        float dr = -er, di = im;
        float den = dr * dr + di * di;
        float nr = ar - 1.0f, ni = ai;
        float cr = (nr * dr + ni * di) / den;
        float ci = (ni * dr - nr * di) / den;
        float br = Br[p * HDIM + h], bi = Bi[p * HDIM + h];
        W1t[(2 * p) * HDIM + h]     = f2bf(cr * br - ci * bi);
        W1t[(2 * p + 1) * HDIM + h] = f2bf(cr * bi + ci * br);
    } else if (blockIdx.x < 2 * PDIM) {
        int p = blockIdx.x - PDIM;
        W2t[h * (2 * PDIM) + 2 * p]     = f2bf(Cr[h * PDIM + p]);
        W2t[h * (2 * PDIM) + 2 * p + 1] = f2bf(-Ci[h * PDIM + p]);
    } else {
        int p = h;
        float er = expf(llr[p]);
        float im = lim[p];
        float d  = expf(ldl[p]);
        float zr = -er * d, zi = im * d;
        float ea = expf(zr);
        float sz, cz; sincosf(zi, &sz, &cz);
        float ar = ea * cz, ai = ea * sz;
        float dr = -er, di = im;
        float den = dr * dr + di * di;
        float nr = ar - 1.0f, ni = ai;
        float cr = (nr * dr + ni * di) / den;
        float ci = (ni * dr - nr * di) / den;
        float eC = expf((float)CHLEN * zr);
        float sC, cC;
        sincosf((float)CHLEN * zi, &sC, &cC);
        par[2 * p]            = ar;
        par[2 * p + 1]        = ai;
        par[512 + 2 * p]      = cr;
        par[512 + 2 * p + 1]  = ci;
        par[1024 + 2 * p]     = eC * cC;
        par[1024 + 2 * p + 1] = eC * sC;
    }
}

// ---------------- fused LayerNorm -> bf16 h ----------------
__global__ void ln_k(const float* __restrict__ u, unsigned short* __restrict__ hbf,
                     const float* __restrict__ gamma, const float* __restrict__ beta) {
    __shared__ float gS[HDIM], bS[HDIM];
    int t = threadIdx.x;
    gS[t] = gamma[t]; bS[t] = beta[t];
    int lane = t & 63, wv = t >> 6;
    int row = blockIdx.x * 4 + wv;
    float4 v = *(const float4*)(u + (size_t)row * HDIM + lane * 4);
    float s  = v.x + v.y + v.z + v.w;
    float sq = v.x * v.x + v.y * v.y + v.z * v.z + v.w * v.w;
    #pragma unroll
    for (int o = 1; o < 64; o <<= 1) { s += __shfl_xor(s, o); sq += __shfl_xor(sq, o); }
    float mu = s * (1.0f / HDIM);
    float rs = rsqrtf(sq * (1.0f / HDIM) - mu * mu + 1e-5f);
    __syncthreads();
    int c = lane * 4;
    ushort4 o;
    o.x = f2bf((v.x - mu) * rs * gS[c + 0] + bS[c + 0]);
    o.y = f2bf((v.y - mu) * rs * gS[c + 1] + bS[c + 1]);
    o.z = f2bf((v.z - mu) * rs * gS[c + 2] + bS[c + 2]);
    o.w = f2bf((v.w - mu) * rs * gS[c + 3] + bS[c + 3]);
    *(ushort4*)(hbf + (size_t)row * HDIM + c) = o;
}

// ---------------- fused GEMM1 + scan_reduce (R9 structure; bounds (256,3)) --------
__launch_bounds__(256, 3)
__global__ void gemm1_reduce_k(const unsigned short* __restrict__ A,
                               const unsigned short* __restrict__ B,
                               unsigned short* __restrict__ Bu,
                               const float* __restrict__ par,
                               float* __restrict__ last) {
    __shared__ __align__(16) unsigned char smem[128 * 66 * 4];   // 33792 B
    unsigned short* As0 = (unsigned short*)smem;                  // As[2][128*32]
    unsigned short* Bs0 = (unsigned short*)(smem + 16384);        // Bs[2][128*32]
    unsigned int*   Cs  = (unsigned int*)smem;                    // overlay, post-loop
    const int t = threadIdx.x;

    constexpr int K = HDIM;        // 256
    constexpr int N = 512;

    // XCD-aware remap
    const int nbn  = (int)gridDim.x;
    const int flat = (int)blockIdx.y * nbn + (int)blockIdx.x;
    const int nwg  = nbn * (int)gridDim.y;
    const int tile = (flat & 7) * (nwg >> 3) + (flat >> 3);
    const int bn = tile % nbn, bm = tile / nbn;

    const int lane = t & 63, w = t >> 6;

    const int srow   = 32 * w + (lane >> 2);
    const int schunk = (lane & 3) ^ ((lane >> 3) & 3);
    const unsigned short* gA = A + (size_t)(bm * 128 + srow) * K + schunk * 8;
    const unsigned short* gB = B + (size_t)(bn * 128 + srow) * K + schunk * 8;
    const int l0 = (32 * w) * 32;
    const int l1 = (32 * w + 16) * 32;

    const int wm = (w & 1) * 64;
    const int wn = (w >> 1) * 64;
    const int mrow = lane & 15;
    const int rsw  = (mrow >> 1) & 3;
    const int cch  = lane >> 4;
    const int fcol = ((cch ^ rsw) * 8);

    f32x4 acc[4][4] = {};
    constexpr int NT = K / 32;     // 8

    gload_lds16(gA,          &As0[0 * 4096 + l0]);
    gload_lds16(gA + 16 * K, &As0[0 * 4096 + l1]);
    gload_lds16(gB,          &Bs0[0 * 4096 + l0]);
    gload_lds16(gB + 16 * K, &Bs0[0 * 4096 + l1]);

    #pragma unroll
    for (int tt = 0; tt < NT; ++tt) {
        const int cur = tt & 1;
        if (tt + 1 < NT) {
            const int k0 = (tt + 1) * 32;
            gload_lds16(gA + k0,          &As0[(cur ^ 1) * 4096 + l0]);
            gload_lds16(gA + 16 * K + k0, &As0[(cur ^ 1) * 4096 + l1]);
            gload_lds16(gB + k0,          &Bs0[(cur ^ 1) * 4096 + l0]);
            gload_lds16(gB + 16 * K + k0, &Bs0[(cur ^ 1) * 4096 + l1]);
            asm volatile("s_waitcnt vmcnt(4)" ::: "memory");
        } else {
            asm volatile("s_waitcnt vmcnt(0)" ::: "memory");
        }
        __builtin_amdgcn_sched_barrier(0);
        __builtin_amdgcn_s_barrier();
        __builtin_amdgcn_sched_barrier(0);

        bf16x8 fa[4], fb[4];
        #pragma unroll
        for (int i = 0; i < 4; i++) {
            fa[i] = *(const bf16x8*)&As0[cur * 4096 + (wm + i * 16 + mrow) * 32 + fcol];
            fb[i] = *(const bf16x8*)&Bs0[cur * 4096 + (wn + i * 16 + mrow) * 32 + fcol];
        }
        __builtin_amdgcn_s_setprio(1);
        #pragma unroll
        for (int i = 0; i < 4; i++)
            #pragma unroll
            for (int j = 0; j < 4; j++)
                acc[i][j] = __builtin_amdgcn_mfma_f32_16x16x32_bf16(fa[i], fb[j], acc[i][j], 0, 0, 0);
        __builtin_amdgcn_s_setprio(0);
        __builtin_amdgcn_sched_barrier(0);
        if (tt + 1 < NT) __builtin_amdgcn_s_barrier();
    }

    __syncthreads();   // all waves done with staging LDS -> safe to overlay Cs

    // epilogue 1: write Bu (unchanged) + same bf16 values into Cs
    unsigned short* CsUS = (unsigned short*)Cs;
    const int r0 = (lane >> 4) * 4;
    const int c0 = lane & 15;
    #pragma unroll
    for (int i = 0; i < 4; i++) {
        #pragma unroll
        for (int r = 0; r < 4; r++) {
            const int row_l = wm + i * 16 + r0 + r;
            const size_t rowoff = (size_t)(bm * 128 + row_l) * N;
            #pragma unroll
            for (int j = 0; j < 4; j++) {
                const int col_l = wn + j * 16 + c0;
                const unsigned short hv = f2bf(acc[i][j][r]);
                Bu[rowoff + bn * 128 + col_l] = hv;
                CsUS[row_l * 132 + col_l]     = hv;   // 132-ushort row stride (pad)
            }
        }
    }
    __syncthreads();

    // epilogue 2: wave g = chunk g; lane = local complex column
    const int g  = w;
    const int pg = bn * 64 + lane;                    // global complex p
    const float ar = par[2 * pg], ai = par[2 * pg + 1];
    float xr = 0.0f, xi = 0.0f;
    const unsigned int* crow = Cs + (size_t)(g * 32) * 66 + lane;
    #pragma unroll 8
    for (int j = 0; j < CHLEN; j++) {
        unsigned int v = crow[(size_t)j * 66];
        float vr = bf2f(v & 0xFFFFu), vi = bf2f(v >> 16);
        float nr = fmaf(ar, xr, fmaf(-ai, xi, vr));
        float ni = fmaf(ar, xi, fmaf(ai, xr, vi));
        xr = nr; xi = ni;
    }
    const int b  = (bm * 128) / LSEQ;                 // batch
    const int cg = ((bm * 128) % LSEQ) / CHLEN + g;   // global chunk
    *(float2*)(last + ((size_t)b * NCHUNK + cg) * 512 + 2 * pg) = make_float2(xr, xi);
}

// ---------------- scan pass 2 (unchanged) ----------------
__global__ void scan_carry_k(const float* __restrict__ last, float* __restrict__ prefix,
                             const float* __restrict__ par) {
    int p = threadIdx.x, b = blockIdx.x;
    float Ar = par[1024 + 2 * p], Ai = par[1024 + 2 * p + 1];
    float Pr = 0.0f, Pi = 0.0f;
    const float2* lp = (const float2*)(last + (size_t)b * NCHUNK * 512) + p;
    float2* pp = (float2*)(prefix + (size_t)b * NCHUNK * 512) + p;
    for (int c0 = 0; c0 < NCHUNK; c0 += 16) {
        float2 v[16];
        #pragma unroll
        for (int j = 0; j < 16; j++) v[j] = lp[(size_t)(c0 + j) * 256];
        #pragma unroll
        for (int j = 0; j < 16; j++) {
            pp[(size_t)(c0 + j) * 256] = make_float2(Pr, Pi);
            float nr = fmaf(Ar, Pr, fmaf(-Ai, Pi, v[j].x));
            float ni = fmaf(Ar, Pi, fmaf(Ai, Pr, v[j].y));
            Pr = nr; Pi = ni;
        }
    }
}

// ---------------- fused scan_apply + GEMM2 ----------------
// R9 Bs-staged structure (the measured-best in the timed run) upgraded to a
// 2-tile-deep wave-private pipeline: Bs is TRIPLE-buffered (3 x 16 KB); at
// step tt we issue tile tt+2 and wait vmcnt(8) -> tile tt landed while
// tt+1/tt+2 (8 loads) stay in flight. 2 steps of MFMA (~256 cy) now cover the
// ~250 cy L2 latency that the 1-deep vmcnt(4) pipeline exposed every step.
// Buffer indices are unroll-constant (static). WAR on buffer (tt+2)%3 =
// (tt-1)%3 is safe: tile tt-1's ds_reads lgkm-completed before its MFMAs,
// which are sched_barrier-pinned before this stage issue. LDS 32+48=80 KB ->
// 2 blocks/CU (same as R9; no occupancy loss).
__launch_bounds__(256, 2)
__global__ void apply_gemm2_k(const unsigned short* __restrict__ Bu,
                              const float* __restrict__ par,
                              const float* __restrict__ prefix,
                              const unsigned short* __restrict__ W2t,
                              const float* __restrict__ u, float* __restrict__ out) {
    __shared__ __align__(16) unsigned short Xs[32 * 512];     // 32 KB, swizzled
    __shared__ __align__(16) unsigned short Bs[3][256 * 32];  // 3 x 16 KB
    const int t = threadIdx.x;
    const int lane = t & 63, w = t >> 6;
    const int c = blockIdx.x, b = blockIdx.y;
    const size_t row0 = (size_t)b * LSEQ + (size_t)c * CHLEN;

    // wave-private W2t staging (involution): call m stages rows 64w+16m+(lane>>2)
    const int schunk = (lane & 3) ^ ((lane >> 3) & 3);
    const unsigned short* gW = W2t + (size_t)(w * 64 + (lane >> 2)) * 512 + schunk * 8;

    // prologue: tiles 0 and 1 issued before phase A (latency hides under it)
    #pragma unroll
    for (int m = 0; m < 4; m++)
        gload_lds16(gW + (size_t)m * 16 * 512,      &Bs[0][(w * 64 + m * 16) * 32]);
    #pragma unroll
    for (int m = 0; m < 4; m++)
        gload_lds16(gW + (size_t)m * 16 * 512 + 32, &Bs[1][(w * 64 + m * 16) * 32]);

    // ---------- phase A: thread p = t owns complex column p ----------
    {
        const unsigned int* q = (const unsigned int*)(Bu + row0 * 512) + t;
        unsigned int vv[32];
        #pragma unroll
        for (int j = 0; j < 32; j++) vv[j] = q[(size_t)j * 256];
        const float2 P = ((const float2*)(prefix + ((size_t)b * NCHUNK + c) * 512))[t];
        const float ar = par[2 * t], ai = par[2 * t + 1];
        float xr = P.x, xi = P.y;
        #pragma unroll
        for (int j = 0; j < 32; j++) {
            float vr = bf2f(vv[j] & 0xFFFFu), vi = bf2f(vv[j] >> 16);
            float nr = fmaf(ar, xr, fmaf(-ai, xi, vr));
            float ni = fmaf(ar, xi, fmaf(ai, xr, vi));
            xr = nr; xi = ni;
            unsigned int pk = (unsigned int)f2bf(xr) | ((unsigned int)f2bf(xi) << 16);
            // Xs[j][.]: 16B-chunk = p>>2, swizzle ^= j&7, word = p&3
            *(unsigned int*)&Xs[j * 512 + ((((t >> 2) ^ (j & 7)) << 3) + (t & 3) * 2)] = pk;
        }
    }

    const int mrow = lane & 15;
    const int rsw  = (mrow >> 1) & 3;
    const int cch  = lane >> 4;
    const int fcol = (cch ^ rsw) * 8;

    f32x4 acc[2][4] = {};
    __syncthreads();            // Xs complete; drains prologue staging too

    #pragma unroll
    for (int tt = 0; tt < 16; tt++) {          // K=512; NO s_barrier in loop
        const int cur = tt % 3;
        if (tt + 2 < 16) {
            const int k0 = (tt + 2) * 32;
            const int nb = (tt + 2) % 3;
            #pragma unroll
            for (int m = 0; m < 4; m++)
                gload_lds16(gW + (size_t)m * 16 * 512 + k0,
                            &Bs[nb][(w * 64 + m * 16) * 32]);
            asm volatile("s_waitcnt vmcnt(8)" ::: "memory");   // tile tt landed; 2 tiles in flight
        } else if (tt + 1 < 16) {
            asm volatile("s_waitcnt vmcnt(4)" ::: "memory");   // tile 14 landed; tile 15 in flight
        } else {
            asm volatile("s_waitcnt vmcnt(0)" ::: "memory");
        }
        __builtin_amdgcn_sched_barrier(0);

        bf16x8 fa[2], fb[4];
        #pragma unroll
        for (int i = 0; i < 2; i++) {
            const int r = i * 16 + mrow;
            fa[i] = *(const bf16x8*)&Xs[r * 512 + (((tt * 4 + cch) ^ (r & 7)) << 3)];
        }
        #pragma unroll
        for (int j = 0; j < 4; j++)
            fb[j] = *(const bf16x8*)&Bs[cur][(w * 64 + j * 16 + mrow) * 32 + fcol];
        __builtin_amdgcn_s_setprio(1);
        #pragma unroll
        for (int i = 0; i < 2; i++)
            #pragma unroll
            for (int j = 0; j < 4; j++)
                acc[i][j] = __builtin_amdgcn_mfma_f32_16x16x32_bf16(fa[i], fb[j], acc[i][j], 0, 0, 0);
        __builtin_amdgcn_s_setprio(0);
        __builtin_amdgcn_sched_barrier(0);     // pin: next stage stays after these MFMAs
    }

    // epilogue: out = u + gelu(acc). Wave w owns out-cols 64w..64w+63.
    const int r0 = (lane >> 4) * 4, c0 = lane & 15;
    #pragma unroll
    for (int i = 0; i < 2; i++) {
        #pragma unroll
        for (int r = 0; r < 4; r++) {
            const size_t rowoff = (row0 + i * 16 + r0 + r) * HDIM;
            #pragma unroll
            for (int j = 0; j < 4; j++) {
                const int col = w * 64 + j * 16 + c0;
                float y = acc[i][j][r];
                float z = 0.7978845608f * fmaf(0.044715f * y * y, y, y);
                float e = __expf(2.0f * z);
                float th = 1.0f - 2.0f / (e + 1.0f);
                float g = 0.5f * y * (1.0f + th);
                out[rowoff + col] = u[rowoff + col] + g;
            }
        }
    }
}

extern "C" void kernel_launch(void* const* d_in, const int* in_sizes, int n_in,
                              void* d_out, int out_size, void* d_ws, size_t ws_size,
                              hipStream_t stream) {
    const float* u   = (const float*)d_in[0];
    const float* llr = (const float*)d_in[1];
    const float* lim = (const float*)d_in[2];
    const float* Br  = (const float*)d_in[3];
    const float* Bi  = (const float*)d_in[4];
    const float* Cr  = (const float*)d_in[5];
    const float* Ci  = (const float*)d_in[6];
    const float* ldl = (const float*)d_in[7];
    const float* gam = (const float*)d_in[8];
    const float* bet = (const float*)d_in[9];
    float* out = (float*)d_out;

    float* ws     = (float*)d_ws;
    float* par    = ws;                                     // 2048 floats
    float* last   = ws + 2048;                              // 2 MB
    float* prefix = last + (size_t)BATCH * NCHUNK * 512;    // 2 MB
    unsigned short* W1t = (unsigned short*)(prefix + (size_t)BATCH * NCHUNK * 512);
    unsigned short* W2t = W1t + 512 * HDIM;                 // [256][512]
    unsigned short* hbf = W2t + HDIM * 512;                 // [32768][256] bf16
    unsigned short* Bu  = hbf + (size_t)MTOT * HDIM;        // [32768][512] bf16

    ln_k<<<MTOT / 4, 256, 0, stream>>>(u, hbf, gam, bet);
    wpack_k<<<2 * PDIM + 1, HDIM, 0, stream>>>(llr, lim, ldl, Br, Bi, Cr, Ci, W1t, W2t, par);

    // fused GEMM1 + chunk-local scan reduction (writes Bu and last)
    gemm1_reduce_k<<<dim3(512 / 128, MTOT / 128), 256, 0, stream>>>(hbf, W1t, Bu, par, last);

    scan_carry_k<<<BATCH, PDIM, 0, stream>>>(last, prefix, par);

    // fused scan_apply + GEMM2: 2-deep triple-buffered wave-private pipeline
    apply_gemm2_k<<<dim3(NCHUNK, BATCH), 256, 0, stream>>>(Bu, par, prefix, W2t, u, out);
}

// Round 12
// 153.191 us; speedup vs baseline: 1.0835x; 1.0107x over previous
//
#include <hip/hip_runtime.h>
#include <math.h>

#define HDIM 256
#define PDIM 256
#define BATCH 8
#define LSEQ 4096
#define MTOT (BATCH * LSEQ)   // 32768
#define NCHUNK 128
#define CHLEN 32              // NCHUNK*CHLEN == LSEQ

typedef __attribute__((ext_vector_type(8))) short bf16x8;   // 8 bf16 = 4 VGPRs
typedef __attribute__((ext_vector_type(4))) float f32x4;

__device__ __forceinline__ unsigned short f2bf(float f) {
    union { float f; unsigned int u; } v; v.f = f;
    unsigned int r = v.u + 0x7FFFu + ((v.u >> 16) & 1u);   // RNE
    return (unsigned short)(r >> 16);
}
__device__ __forceinline__ float bf2f(unsigned int lo16) {
    union { unsigned int u; float f; } v; v.u = lo16 << 16;
    return v.f;
}

// async global->LDS, 16B per lane; LDS dest is wave-uniform base + lane*16
__device__ __forceinline__ void gload_lds16(const void* g, void* l) {
    __builtin_amdgcn_global_load_lds(
        (const __attribute__((address_space(1))) void*)g,
        (__attribute__((address_space(3))) void*)l, 16, 0, 0);
}

// ---------------- merged setup + LayerNorm in ONE launch ----------------
// blocks [0,PDIM): W1t rows; [PDIM,2*PDIM): W2t rows; 2*PDIM: par;
// (2*PDIM, 2*PDIM+8192]: LayerNorm (4 rows per block). One fewer launch gap.
// par floats: [0:512) a  [512:1024) coef  [1024:1536) a^CHLEN  (interleaved r,i)
// W1t[n][k]: n=2p -> Re(coef_p * B_tilde[p][k]); n=2p+1 -> Im. (bf16, [512][256])
// W2t[h][2p] = Cr[h][p]; W2t[h][2p+1] = -Ci[h][p]. (bf16, [256][512])
__global__ void setup_ln_k(const float* __restrict__ llr, const float* __restrict__ lim,
                           const float* __restrict__ ldl,
                           const float* __restrict__ Br, const float* __restrict__ Bi,
                           const float* __restrict__ Cr, const float* __restrict__ Ci,
                           unsigned short* __restrict__ W1t, unsigned short* __restrict__ W2t,
                           float* __restrict__ par,
                           const float* __restrict__ u, unsigned short* __restrict__ hbf,
                           const float* __restrict__ gamma, const float* __restrict__ beta) {
    __shared__ float gS[HDIM], bS[HDIM];
    int h = threadIdx.x;
    if (blockIdx.x < PDIM) {
        int p = blockIdx.x;
        float er = expf(llr[p]);
        float im = lim[p];
        float d  = expf(ldl[p]);
        float zr = -er * d, zi = im * d;
        float ea = expf(zr);
        float sz, cz; sincosf(zi, &sz, &cz);
        float ar = ea * cz, ai = ea * sz;
        float dr = -er, di = im;
        float den = dr * dr + di * di;
        float nr = ar - 1.0f, ni = ai;
        float cr = (nr * dr + ni * di) / den;
        float ci = (ni * dr - nr * di) / den;
        float br = Br[p * HDIM + h], bi = Bi[p * HDIM + h];
        W1t[(2 * p) * HDIM + h]     = f2bf(cr * br - ci * bi);
        W1t[(2 * p + 1) * HDIM + h] = f2bf(cr * bi + ci * br);
    } else if (blockIdx.x < 2 * PDIM) {
        int p = blockIdx.x - PDIM;
        W2t[h * (2 * PDIM) + 2 * p]     = f2bf(Cr[h * PDIM + p]);
        W2t[h * (2 * PDIM) + 2 * p + 1] = f2bf(-Ci[h * PDIM + p]);
    } else if (blockIdx.x == 2 * PDIM) {
        int p = h;
        float er = expf(llr[p]);
        float im = lim[p];
        float d  = expf(ldl[p]);
        float zr = -er * d, zi = im * d;
        float ea = expf(zr);
        float sz, cz; sincosf(zi, &sz, &cz);
        float ar = ea * cz, ai = ea * sz;
        float dr = -er, di = im;
        float den = dr * dr + di * di;
        float nr = ar - 1.0f, ni = ai;
        float cr = (nr * dr + ni * di) / den;
        float ci = (ni * dr - nr * di) / den;
        float eC = expf((float)CHLEN * zr);
        float sC, cC;
        sincosf((float)CHLEN * zi, &sC, &cC);
        par[2 * p]            = ar;
        par[2 * p + 1]        = ai;
        par[512 + 2 * p]      = cr;
        par[512 + 2 * p + 1]  = ci;
        par[1024 + 2 * p]     = eC * cC;
        par[1024 + 2 * p + 1] = eC * sC;
    } else {
        // ---------------- fused LayerNorm -> bf16 h (math identical to ln_k) ----
        int t = h;
        gS[t] = gamma[t]; bS[t] = beta[t];
        int lane = t & 63, wv = t >> 6;
        int row = (int)(blockIdx.x - (2 * PDIM + 1)) * 4 + wv;
        float4 v = *(const float4*)(u + (size_t)row * HDIM + lane * 4);
        float s  = v.x + v.y + v.z + v.w;
        float sq = v.x * v.x + v.y * v.y + v.z * v.z + v.w * v.w;
        #pragma unroll
        for (int o = 1; o < 64; o <<= 1) { s += __shfl_xor(s, o); sq += __shfl_xor(sq, o); }
        float mu = s * (1.0f / HDIM);
        float rs = rsqrtf(sq * (1.0f / HDIM) - mu * mu + 1e-5f);
        __syncthreads();
        int c = lane * 4;
        ushort4 o;
        o.x = f2bf((v.x - mu) * rs * gS[c + 0] + bS[c + 0]);
        o.y = f2bf((v.y - mu) * rs * gS[c + 1] + bS[c + 1]);
        o.z = f2bf((v.z - mu) * rs * gS[c + 2] + bS[c + 2]);
        o.w = f2bf((v.w - mu) * rs * gS[c + 3] + bS[c + 3]);
        *(ushort4*)(hbf + (size_t)row * HDIM + c) = o;
    }
}

// ---------------- fused GEMM1 + scan_reduce (R11, unchanged) ----------------
__launch_bounds__(256, 3)
__global__ void gemm1_reduce_k(const unsigned short* __restrict__ A,
                               const unsigned short* __restrict__ B,
                               unsigned short* __restrict__ Bu,
                               const float* __restrict__ par,
                               float* __restrict__ last) {
    __shared__ __align__(16) unsigned char smem[128 * 66 * 4];   // 33792 B
    unsigned short* As0 = (unsigned short*)smem;                  // As[2][128*32]
    unsigned short* Bs0 = (unsigned short*)(smem + 16384);        // Bs[2][128*32]
    unsigned int*   Cs  = (unsigned int*)smem;                    // overlay, post-loop
    const int t = threadIdx.x;

    constexpr int K = HDIM;        // 256
    constexpr int N = 512;

    // XCD-aware remap
    const int nbn  = (int)gridDim.x;
    const int flat = (int)blockIdx.y * nbn + (int)blockIdx.x;
    const int nwg  = nbn * (int)gridDim.y;
    const int tile = (flat & 7) * (nwg >> 3) + (flat >> 3);
    const int bn = tile % nbn, bm = tile / nbn;

    const int lane = t & 63, w = t >> 6;

    const int srow   = 32 * w + (lane >> 2);
    const int schunk = (lane & 3) ^ ((lane >> 3) & 3);
    const unsigned short* gA = A + (size_t)(bm * 128 + srow) * K + schunk * 8;
    const unsigned short* gB = B + (size_t)(bn * 128 + srow) * K + schunk * 8;
    const int l0 = (32 * w) * 32;
    const int l1 = (32 * w + 16) * 32;

    const int wm = (w & 1) * 64;
    const int wn = (w >> 1) * 64;
    const int mrow = lane & 15;
    const int rsw  = (mrow >> 1) & 3;
    const int cch  = lane >> 4;
    const int fcol = ((cch ^ rsw) * 8);

    f32x4 acc[4][4] = {};
    constexpr int NT = K / 32;     // 8

    gload_lds16(gA,          &As0[0 * 4096 + l0]);
    gload_lds16(gA + 16 * K, &As0[0 * 4096 + l1]);
    gload_lds16(gB,          &Bs0[0 * 4096 + l0]);
    gload_lds16(gB + 16 * K, &Bs0[0 * 4096 + l1]);

    #pragma unroll
    for (int tt = 0; tt < NT; ++tt) {
        const int cur = tt & 1;
        if (tt + 1 < NT) {
            const int k0 = (tt + 1) * 32;
            gload_lds16(gA + k0,          &As0[(cur ^ 1) * 4096 + l0]);
            gload_lds16(gA + 16 * K + k0, &As0[(cur ^ 1) * 4096 + l1]);
            gload_lds16(gB + k0,          &Bs0[(cur ^ 1) * 4096 + l0]);
            gload_lds16(gB + 16 * K + k0, &Bs0[(cur ^ 1) * 4096 + l1]);
            asm volatile("s_waitcnt vmcnt(4)" ::: "memory");
        } else {
            asm volatile("s_waitcnt vmcnt(0)" ::: "memory");
        }
        __builtin_amdgcn_sched_barrier(0);
        __builtin_amdgcn_s_barrier();
        __builtin_amdgcn_sched_barrier(0);

        bf16x8 fa[4], fb[4];
        #pragma unroll
        for (int i = 0; i < 4; i++) {
            fa[i] = *(const bf16x8*)&As0[cur * 4096 + (wm + i * 16 + mrow) * 32 + fcol];
            fb[i] = *(const bf16x8*)&Bs0[cur * 4096 + (wn + i * 16 + mrow) * 32 + fcol];
        }
        __builtin_amdgcn_s_setprio(1);
        #pragma unroll
        for (int i = 0; i < 4; i++)
            #pragma unroll
            for (int j = 0; j < 4; j++)
                acc[i][j] = __builtin_amdgcn_mfma_f32_16x16x32_bf16(fa[i], fb[j], acc[i][j], 0, 0, 0);
        __builtin_amdgcn_s_setprio(0);
        __builtin_amdgcn_sched_barrier(0);
        if (tt + 1 < NT) __builtin_amdgcn_s_barrier();
    }

    __syncthreads();   // all waves done with staging LDS -> safe to overlay Cs

    // epilogue 1: write Bu (unchanged) + same bf16 values into Cs
    unsigned short* CsUS = (unsigned short*)Cs;
    const int r0 = (lane >> 4) * 4;
    const int c0 = lane & 15;
    #pragma unroll
    for (int i = 0; i < 4; i++) {
        #pragma unroll
        for (int r = 0; r < 4; r++) {
            const int row_l = wm + i * 16 + r0 + r;
            const size_t rowoff = (size_t)(bm * 128 + row_l) * N;
            #pragma unroll
            for (int j = 0; j < 4; j++) {
                const int col_l = wn + j * 16 + c0;
                const unsigned short hv = f2bf(acc[i][j][r]);
                Bu[rowoff + bn * 128 + col_l] = hv;
                CsUS[row_l * 132 + col_l]     = hv;   // 132-ushort row stride (pad)
            }
        }
    }
    __syncthreads();

    // epilogue 2: wave g = chunk g; lane = local complex column
    const int g  = w;
    const int pg = bn * 64 + lane;                    // global complex p
    const float ar = par[2 * pg], ai = par[2 * pg + 1];
    float xr = 0.0f, xi = 0.0f;
    const unsigned int* crow = Cs + (size_t)(g * 32) * 66 + lane;
    #pragma unroll 8
    for (int j = 0; j < CHLEN; j++) {
        unsigned int v = crow[(size_t)j * 66];
        float vr = bf2f(v & 0xFFFFu), vi = bf2f(v >> 16);
        float nr = fmaf(ar, xr, fmaf(-ai, xi, vr));
        float ni = fmaf(ar, xi, fmaf(ai, xr, vi));
        xr = nr; xi = ni;
    }
    const int b  = (bm * 128) / LSEQ;                 // batch
    const int cg = ((bm * 128) % LSEQ) / CHLEN + g;   // global chunk
    *(float2*)(last + ((size_t)b * NCHUNK + cg) * 512 + 2 * pg) = make_float2(xr, xi);
}

// ---------------- scan pass 2 (unchanged) ----------------
__global__ void scan_carry_k(const float* __restrict__ last, float* __restrict__ prefix,
                             const float* __restrict__ par) {
    int p = threadIdx.x, b = blockIdx.x;
    float Ar = par[1024 + 2 * p], Ai = par[1024 + 2 * p + 1];
    float Pr = 0.0f, Pi = 0.0f;
    const float2* lp = (const float2*)(last + (size_t)b * NCHUNK * 512) + p;
    float2* pp = (float2*)(prefix + (size_t)b * NCHUNK * 512) + p;
    for (int c0 = 0; c0 < NCHUNK; c0 += 16) {
        float2 v[16];
        #pragma unroll
        for (int j = 0; j < 16; j++) v[j] = lp[(size_t)(c0 + j) * 256];
        #pragma unroll
        for (int j = 0; j < 16; j++) {
            pp[(size_t)(c0 + j) * 256] = make_float2(Pr, Pi);
            float nr = fmaf(Ar, Pr, fmaf(-Ai, Pi, v[j].x));
            float ni = fmaf(Ar, Pi, fmaf(Ai, Pr, v[j].y));
            Pr = nr; Pi = ni;
        }
    }
}

// ---------------- fused scan_apply + GEMM2 (R11, unchanged) ----------------
__launch_bounds__(256, 2)
__global__ void apply_gemm2_k(const unsigned short* __restrict__ Bu,
                              const float* __restrict__ par,
                              const float* __restrict__ prefix,
                              const unsigned short* __restrict__ W2t,
                              const float* __restrict__ u, float* __restrict__ out) {
    __shared__ __align__(16) unsigned short Xs[32 * 512];     // 32 KB, swizzled
    __shared__ __align__(16) unsigned short Bs[3][256 * 32];  // 3 x 16 KB
    const int t = threadIdx.x;
    const int lane = t & 63, w = t >> 6;
    const int c = blockIdx.x, b = blockIdx.y;
    const size_t row0 = (size_t)b * LSEQ + (size_t)c * CHLEN;

    // wave-private W2t staging (involution): call m stages rows 64w+16m+(lane>>2)
    const int schunk = (lane & 3) ^ ((lane >> 3) & 3);
    const unsigned short* gW = W2t + (size_t)(w * 64 + (lane >> 2)) * 512 + schunk * 8;

    // prologue: tiles 0 and 1 issued before phase A (latency hides under it)
    #pragma unroll
    for (int m = 0; m < 4; m++)
        gload_lds16(gW + (size_t)m * 16 * 512,      &Bs[0][(w * 64 + m * 16) * 32]);
    #pragma unroll
    for (int m = 0; m < 4; m++)
        gload_lds16(gW + (size_t)m * 16 * 512 + 32, &Bs[1][(w * 64 + m * 16) * 32]);

    // ---------- phase A: thread p = t owns complex column p ----------
    {
        const unsigned int* q = (const unsigned int*)(Bu + row0 * 512) + t;
        unsigned int vv[32];
        #pragma unroll
        for (int j = 0; j < 32; j++) vv[j] = q[(size_t)j * 256];
        const float2 P = ((const float2*)(prefix + ((size_t)b * NCHUNK + c) * 512))[t];
        const float ar = par[2 * t], ai = par[2 * t + 1];
        float xr = P.x, xi = P.y;
        #pragma unroll
        for (int j = 0; j < 32; j++) {
            float vr = bf2f(vv[j] & 0xFFFFu), vi = bf2f(vv[j] >> 16);
            float nr = fmaf(ar, xr, fmaf(-ai, xi, vr));
            float ni = fmaf(ar, xi, fmaf(ai, xr, vi));
            xr = nr; xi = ni;
            unsigned int pk = (unsigned int)f2bf(xr) | ((unsigned int)f2bf(xi) << 16);
            // Xs[j][.]: 16B-chunk = p>>2, swizzle ^= j&7, word = p&3
            *(unsigned int*)&Xs[j * 512 + ((((t >> 2) ^ (j & 7)) << 3) + (t & 3) * 2)] = pk;
        }
    }

    const int mrow = lane & 15;
    const int rsw  = (mrow >> 1) & 3;
    const int cch  = lane >> 4;
    const int fcol = (cch ^ rsw) * 8;

    f32x4 acc[2][4] = {};
    __syncthreads();            // Xs complete; drains prologue staging too

    #pragma unroll
    for (int tt = 0; tt < 16; tt++) {          // K=512; NO s_barrier in loop
        const int cur = tt % 3;
        if (tt + 2 < 16) {
            const int k0 = (tt + 2) * 32;
            const int nb = (tt + 2) % 3;
            #pragma unroll
            for (int m = 0; m < 4; m++)
                gload_lds16(gW + (size_t)m * 16 * 512 + k0,
                            &Bs[nb][(w * 64 + m * 16) * 32]);
            asm volatile("s_waitcnt vmcnt(8)" ::: "memory");   // tile tt landed; 2 tiles in flight
        } else if (tt + 1 < 16) {
            asm volatile("s_waitcnt vmcnt(4)" ::: "memory");   // tile 14 landed; tile 15 in flight
        } else {
            asm volatile("s_waitcnt vmcnt(0)" ::: "memory");
        }
        __builtin_amdgcn_sched_barrier(0);

        bf16x8 fa[2], fb[4];
        #pragma unroll
        for (int i = 0; i < 2; i++) {
            const int r = i * 16 + mrow;
            fa[i] = *(const bf16x8*)&Xs[r * 512 + (((tt * 4 + cch) ^ (r & 7)) << 3)];
        }
        #pragma unroll
        for (int j = 0; j < 4; j++)
            fb[j] = *(const bf16x8*)&Bs[cur][(w * 64 + j * 16 + mrow) * 32 + fcol];
        __builtin_amdgcn_s_setprio(1);
        #pragma unroll
        for (int i = 0; i < 2; i++)
            #pragma unroll
            for (int j = 0; j < 4; j++)
                acc[i][j] = __builtin_amdgcn_mfma_f32_16x16x32_bf16(fa[i], fb[j], acc[i][j], 0, 0, 0);
        __builtin_amdgcn_s_setprio(0);
        __builtin_amdgcn_sched_barrier(0);     // pin: next stage stays after these MFMAs
    }

    // epilogue: out = u + gelu(acc). Wave w owns out-cols 64w..64w+63.
    const int r0 = (lane >> 4) * 4, c0 = lane & 15;
    #pragma unroll
    for (int i = 0; i < 2; i++) {
        #pragma unroll
        for (int r = 0; r < 4; r++) {
            const size_t rowoff = (row0 + i * 16 + r0 + r) * HDIM;
            #pragma unroll
            for (int j = 0; j < 4; j++) {
                const int col = w * 64 + j * 16 + c0;
                float y = acc[i][j][r];
                float z = 0.7978845608f * fmaf(0.044715f * y * y, y, y);
                float e = __expf(2.0f * z);
                float th = 1.0f - 2.0f / (e + 1.0f);
                float g = 0.5f * y * (1.0f + th);
                out[rowoff + col] = u[rowoff + col] + g;
            }
        }
    }
}

extern "C" void kernel_launch(void* const* d_in, const int* in_sizes, int n_in,
                              void* d_out, int out_size, void* d_ws, size_t ws_size,
                              hipStream_t stream) {
    const float* u   = (const float*)d_in[0];
    const float* llr = (const float*)d_in[1];
    const float* lim = (const float*)d_in[2];
    const float* Br  = (const float*)d_in[3];
    const float* Bi  = (const float*)d_in[4];
    const float* Cr  = (const float*)d_in[5];
    const float* Ci  = (const float*)d_in[6];
    const float* ldl = (const float*)d_in[7];
    const float* gam = (const float*)d_in[8];
    const float* bet = (const float*)d_in[9];
    float* out = (float*)d_out;

    float* ws     = (float*)d_ws;
    float* par    = ws;                                     // 2048 floats
    float* last   = ws + 2048;                              // 2 MB
    float* prefix = last + (size_t)BATCH * NCHUNK * 512;    // 2 MB
    unsigned short* W1t = (unsigned short*)(prefix + (size_t)BATCH * NCHUNK * 512);
    unsigned short* W2t = W1t + 512 * HDIM;                 // [256][512]
    unsigned short* hbf = W2t + HDIM * 512;                 // [32768][256] bf16
    unsigned short* Bu  = hbf + (size_t)MTOT * HDIM;        // [32768][512] bf16

    // merged setup + LN: one launch (W1t, W2t, par, hbf)
    setup_ln_k<<<2 * PDIM + 1 + MTOT / 4, 256, 0, stream>>>(
        llr, lim, ldl, Br, Bi, Cr, Ci, W1t, W2t, par, u, hbf, gam, bet);

    // fused GEMM1 + chunk-local scan reduction (writes Bu and last)
    gemm1_reduce_k<<<dim3(512 / 128, MTOT / 128), 256, 0, stream>>>(hbf, W1t, Bu, par, last);

    scan_carry_k<<<BATCH, PDIM, 0, stream>>>(last, prefix, par);

    // fused scan_apply + GEMM2: 2-deep triple-buffered wave-private pipeline
    apply_gemm2_k<<<dim3(NCHUNK, BATCH), 256, 0, stream>>>(Bu, par, prefix, W2t, u, out);
}